// Round 6
// baseline (4320.606 us; speedup 1.0000x reference)
//
#include <hip/hip_runtime.h>
#include <hip/hip_bf16.h>

// ---------------- problem constants ----------------
#define NA 10
#define NB 1024
#define NY 94
#define NR 256
#define NH 128
#define NT 50
#define FSC 0.1f
#define NIN 350
#define K1 352            // padded enc K: [h(256) | y(94) | pad(2)]
#define ENC_S 360         // enc LDS row stride (fp8 bytes), 8-aligned, odd-ish dword phase
#define H_S 257           // h carry stride (fp32 elems)
#define D_S 136           // d1/d2 LDS row stride (fp8 bytes)
#define BT 32             // batch rows per block
#define NBLK 320          // 10 agents x 32 tiles
#define LOG2PI 1.8378770664093453f

typedef __attribute__((ext_vector_type(4))) float frag_f32;

__device__ __forceinline__ frag_f32 mfma_fp8(long a, long b, frag_f32 c) {
    return __builtin_amdgcn_mfma_f32_16x16x32_fp8_fp8(a, b, c, 0, 0, 0);
}

// ---- OCP e4m3fn encode/decode (bit-exact vs HW MFMA decode) ----
__device__ __forceinline__ unsigned char f2e4m3(float x) {
    unsigned int u = __float_as_uint(x);
    unsigned char s = (unsigned char)((u >> 24) & 0x80u);
    unsigned int a = u & 0x7FFFFFFFu;
    float af = __uint_as_float(a);
    if (af >= 448.f) return s | 0x7Eu;
    if (af < 0x1p-10f) return s;
    int e = (int)(a >> 23) - 127;
    if (e >= -6) {
        unsigned int r = a + 0x7FFFFu + ((a >> 20) & 1u);   // RTNE to 3 mantissa bits
        int e2 = (int)(r >> 23) - 127;
        unsigned int m = (r >> 20) & 7u;
        if (e2 > 8 || (e2 == 8 && m > 6)) return s | 0x7Eu;
        return s | (unsigned char)(((e2 + 7) << 3) | m);
    } else {
        int qi = (int)rintf(af * 512.f);                     // subnormal grid 2^-9
        return s | (unsigned char)qi;                        // qi==8 -> 0x08 == 2^-6, correct
    }
}
__device__ __forceinline__ float e4m32f(unsigned char v) {
    unsigned int em = v & 0x7Fu;
    float f;
    if (em >= 8u) f = __uint_as_float((((em >> 3) + 120u) << 23) | ((em & 7u) << 20));
    else          f = (float)em * 0x1p-9f;
    return (v & 0x80u) ? -f : f;
}
__device__ __forceinline__ float sigm(float x) { return 1.f / (1.f + __expf(-x)); }
__device__ __forceinline__ float tanh_c(float x) {
    float xx = fminf(fmaxf(x, -15.f), 15.f);
    float e = __expf(2.f * xx);
    return (e - 1.f) / (e + 1.f);
}
__device__ __forceinline__ float softp(float x) {
    return fmaxf(x, 0.f) + log1pf(__expf(-fabsf(x)));
}

// ---------------- prep kernels (fp8 out) ----------------
__global__ void k_prep_wrz(const float* __restrict__ w_ih, const float* __restrict__ w_hh,
                           unsigned char* __restrict__ dst) {
    int i = blockIdx.x * 256 + threadIdx.x;
    if (i >= NA * 512 * K1) return;
    int k = i % K1;
    int g = (i / K1) % 512;
    int a = i / (K1 * 512);
    float v = 0.f;
    if (k < 256)      v = w_ih[(size_t)(a * 768 + g) * NIN + NY + k] + w_hh[(size_t)(a * 768 + g) * NR + k];
    else if (k < 350) v = w_ih[(size_t)(a * 768 + g) * NIN + (k - 256)];
    dst[i] = f2e4m3(v);
}
__global__ void k_prep_wni(const float* __restrict__ w_ih, unsigned char* __restrict__ dst) {
    int i = blockIdx.x * 256 + threadIdx.x;
    if (i >= NA * 256 * K1) return;
    int k = i % K1;
    int g = (i / K1) % 256;
    int a = i / (K1 * 256);
    float v = 0.f;
    if (k < 256)      v = w_ih[(size_t)(a * 768 + 512 + g) * NIN + NY + k];
    else if (k < 350) v = w_ih[(size_t)(a * 768 + 512 + g) * NIN + (k - 256)];
    dst[i] = f2e4m3(v);
}
__global__ void k_prep_wnh(const float* __restrict__ w_hh, unsigned char* __restrict__ dst) {
    int i = blockIdx.x * 256 + threadIdx.x;
    if (i >= NA * 256 * NR) return;
    int k = i % NR;
    int g = (i / NR) % 256;
    int a = i / (NR * 256);
    dst[i] = f2e4m3(w_hh[(size_t)(a * 768 + 512 + g) * NR + k]);
}
__global__ void k_convert(const float* __restrict__ src, unsigned char* __restrict__ dst, int n) {
    int i = blockIdx.x * 256 + threadIdx.x;
    if (i < n) dst[i] = f2e4m3(src[i]);
}

// ---------------- main persistent kernel ----------------
// 1024 threads = 16 waves; 2 blocks/CU (8 waves/SIMD). Wave w: GRU cols [w*16, w*16+16).
__launch_bounds__(1024, 8)
__global__ void k_main(const float* __restrict__ states,
                       const unsigned char* __restrict__ Wrz,  // [A][512][352]
                       const unsigned char* __restrict__ Wni,  // [A][256][352]
                       const unsigned char* __restrict__ Wnh,  // [A][256][256]
                       const unsigned char* __restrict__ D1w,  // [A][128][256]
                       const unsigned char* __restrict__ D2w,  // [A][128][128]
                       const float* __restrict__ b_ih, const float* __restrict__ b_hh,
                       const float* __restrict__ d1_b, const float* __restrict__ d2_b,
                       const float* __restrict__ m_w,  const float* __restrict__ m_b,
                       const float* __restrict__ s_w,  const float* __restrict__ s_b,
                       int* __restrict__ ctrl,
                       float* __restrict__ out)
{
    __shared__ unsigned char enc[2][BT * ENC_S]; // 2 x 11,520 B  [h(256)|y(94)|pad]
    __shared__ float         h_lds[BT * H_S];    // 32,896 B fp32 carry
    __shared__ unsigned char d1buf[BT * D_S];    //  4,352 B
    __shared__ unsigned char d2buf[BT * D_S];    //  4,352 B
    __shared__ float         wls[4 * NH];        //  2,048 B head weights
    __shared__ int s_p;

    const int tid = threadIdx.x;

    // XCD-measured work claim: 40 slots per XCD -> ~1.25 agents per XCD
    if (tid == 0) {
        unsigned int xcc = __builtin_amdgcn_s_getreg(63508) & 7u; // HW_REG_XCC_ID
        int slot = atomicAdd(&ctrl[xcc], 1);
        int p = -1;
        if (slot < 40) {
            int cand = (int)xcc * 40 + slot;
            if (atomicCAS(&ctrl[16 + cand], 0, 1) == 0) p = cand;
        }
        for (int i = 0; p < 0 && i < NBLK; ++i) {
            int cand = ((int)xcc * 40 + i) % NBLK;
            if (atomicCAS(&ctrl[16 + cand], 0, 1) == 0) p = cand;
        }
        s_p = p;
    }
    for (int i = tid; i < BT * ENC_S; i += 1024) { enc[0][i] = 0; enc[1][i] = 0; }
    for (int i = tid; i < BT * H_S;   i += 1024) h_lds[i] = 0.f;
    __syncthreads();

    const int p  = s_p;                 // 0..319
    const int a  = p >> 5;              // agent
    const int b0 = (p & 31) * BT;       // batch tile base

    const int w    = tid >> 6;
    const int lane = tid & 63;
    const int quad = lane >> 4;
    const int l16  = lane & 15;
    const int c0   = w * 16;
    const int koff = quad * 8;

    const unsigned char* Wrza = Wrz + (size_t)a * 512 * K1;
    const unsigned char* Wnia = Wni + (size_t)a * 256 * K1;
    const unsigned char* Wnha = Wnh + (size_t)a * 256 * NR;
    const unsigned char* D1a  = D1w + (size_t)a * NH * NR;
    const unsigned char* D2a  = D2w + (size_t)a * NH * NH;

    const unsigned char* rowR  = Wrza + (size_t)(      c0 + l16) * K1;
    const unsigned char* rowZ  = Wrza + (size_t)(256 + c0 + l16) * K1;
    const unsigned char* rowI  = Wnia + (size_t)(c0 + l16) * K1;
    const unsigned char* rowH  = Wnha + (size_t)(c0 + l16) * NR;
    const unsigned char* rowD1 = D1a  + (size_t)(c0 + l16) * NR;

    if (tid < 512) {
        int o = tid >> 7, k = tid & 127;
        wls[tid] = (o < 2) ? m_w[(size_t)(a * 2 + o) * NH + k]
                           : s_w[(size_t)(a * 2 + (o - 2)) * NH + k];
    }
    // stage y_0 into enc[0]
    {
        const int row = tid >> 5, c3 = (tid & 31) * 3;
        const float* yp = states + (((size_t)0 * NA + a) * NB + (b0 + row)) * NY;
        #pragma unroll
        for (int j = 0; j < 3; ++j) {
            int c = c3 + j;
            if (c < NY) enc[0][row * ENC_S + 256 + c] = f2e4m3(yp[c]);
        }
    }
    float accL = 0.f, accEp = 0.f, accEv = 0.f;
    __syncthreads();

    const frag_f32 z4 = {0.f, 0.f, 0.f, 0.f};

    for (int t = 0; t < NT; ++t) {
        unsigned char* cur = enc[t & 1];
        unsigned char* nxt = enc[(t + 1) & 1];

        // ============ pass A: rz GEMM (K=352) + d1 GEMM (K=256, waves 0-7) ============
        frag_f32 Cr[2], Cz[2], Cd1[2];
        #pragma unroll
        for (int mt = 0; mt < 2; ++mt) { Cr[mt] = z4; Cz[mt] = z4; Cd1[mt] = z4; }
        long bR[2], bZ[2], bD1[2];
        bR[0] = *(const long*)&rowR[koff];
        bZ[0] = *(const long*)&rowZ[koff];
        if (w < 8) bD1[0] = *(const long*)&rowD1[koff];
        #pragma unroll
        for (int ks = 0; ks < 11; ++ks) {
            const int cb = ks & 1, nb = cb ^ 1;
            if (ks < 10) {
                const int kk = (ks + 1) * 32 + koff;
                bR[nb] = *(const long*)&rowR[kk];
                bZ[nb] = *(const long*)&rowZ[kk];
                if (w < 8 && ks < 7) bD1[nb] = *(const long*)&rowD1[kk];
            }
            const int kk = ks * 32 + koff;
            long am[2];
            #pragma unroll
            for (int mt = 0; mt < 2; ++mt)
                am[mt] = *(const long*)&cur[(mt * 16 + l16) * ENC_S + kk];
            #pragma unroll
            for (int mt = 0; mt < 2; ++mt) {
                Cr[mt] = mfma_fp8(am[mt], bR[cb], Cr[mt]);
                Cz[mt] = mfma_fp8(am[mt], bZ[cb], Cz[mt]);
            }
            if (w < 8 && ks < 8) {
                #pragma unroll
                for (int mt = 0; mt < 2; ++mt) Cd1[mt] = mfma_fp8(am[mt], bD1[cb], Cd1[mt]);
            }
        }
        // ---- epilogue A: d1 relu -> fp8 store; r,z -> sigmoid in regs ----
        if (w < 8) {
            const float db = d1_b[a * NH + c0 + l16];
            #pragma unroll
            for (int mt = 0; mt < 2; ++mt)
                #pragma unroll
                for (int rg = 0; rg < 4; ++rg) {
                    const int row = mt * 16 + quad * 4 + rg;
                    float v = Cd1[mt][rg] + db;
                    d1buf[row * D_S + c0 + l16] = f2e4m3(v > 0.f ? v : 0.f);
                }
        }
        {
            const int col = c0 + l16;
            const float brz = b_ih[a * 768 + col]       + b_hh[a * 768 + col];
            const float bzz = b_ih[a * 768 + 256 + col] + b_hh[a * 768 + 256 + col];
            #pragma unroll
            for (int mt = 0; mt < 2; ++mt)
                #pragma unroll
                for (int rg = 0; rg < 4; ++rg) {
                    Cr[mt][rg] = sigm(Cr[mt][rg] + brz);
                    Cz[mt][rg] = sigm(Cz[mt][rg] + bzz);
                }
        }

        // ============ pass B: i_n (K=352) + h_n (K=256) ============
        frag_f32 Ci[2], Ch[2];
        #pragma unroll
        for (int mt = 0; mt < 2; ++mt) { Ci[mt] = z4; Ch[mt] = z4; }
        long bI[2], bH[2];
        bI[0] = *(const long*)&rowI[koff];
        bH[0] = *(const long*)&rowH[koff];
        #pragma unroll
        for (int ks = 0; ks < 11; ++ks) {
            const int cb = ks & 1, nb = cb ^ 1;
            if (ks < 10) {
                const int kk = (ks + 1) * 32 + koff;
                bI[nb] = *(const long*)&rowI[kk];
                if (ks < 7) bH[nb] = *(const long*)&rowH[kk];
            }
            const int kk = ks * 32 + koff;
            long am[2];
            #pragma unroll
            for (int mt = 0; mt < 2; ++mt)
                am[mt] = *(const long*)&cur[(mt * 16 + l16) * ENC_S + kk];
            #pragma unroll
            for (int mt = 0; mt < 2; ++mt) {
                Ci[mt] = mfma_fp8(am[mt], bI[cb], Ci[mt]);
                if (ks < 8) Ch[mt] = mfma_fp8(am[mt], bH[cb], Ch[mt]);
            }
        }
        // ---- epilogue B: gates, fp32 h carry in LDS, fp8 h to nxt ----
        {
            const int col = c0 + l16;
            const float bin = b_ih[a * 768 + 512 + col];
            const float bhn = b_hh[a * 768 + 512 + col];
            #pragma unroll
            for (int mt = 0; mt < 2; ++mt)
                #pragma unroll
                for (int rg = 0; rg < 4; ++rg) {
                    const int row = mt * 16 + quad * 4 + rg;
                    const float r = Cr[mt][rg];
                    const float z = Cz[mt][rg];
                    const float n = tanh_c(Ci[mt][rg] + bin + r * (Ch[mt][rg] + bhn));
                    const float hold = h_lds[row * H_S + col];
                    const float hnew = (1.f - z) * n + z * hold;
                    h_lds[row * H_S + col] = hnew;
                    nxt[row * ENC_S + col] = f2e4m3(hnew);
                }
        }
        // ---- stage y_{t+1} into nxt ----
        {
            const int row = tid >> 5, c3 = (tid & 31) * 3;
            const float* yp = states + (((size_t)(t + 1) * NA + a) * NB + (b0 + row)) * NY;
            #pragma unroll
            for (int j = 0; j < 3; ++j) {
                int c = c3 + j;
                if (c < NY) nxt[row * ENC_S + 256 + c] = f2e4m3(yp[c]);
            }
        }
        // ---- prefetch d2 weights (global only) ----
        const int dcol2 = (w >> 1) * 16;
        const int m2    = (w & 1);           // d2 row tile (16 rows)
        long bD2[4];
        #pragma unroll
        for (int ks = 0; ks < 4; ++ks)
            bD2[ks] = *(const long*)&D2a[(size_t)(dcol2 + l16) * NH + ks * 32 + koff];
        __syncthreads();   // barrier 1 of 2

        // ============ pass C: d2 GEMM (K=128), all 16 waves ============
        frag_f32 Cd2 = z4;
        #pragma unroll
        for (int ks = 0; ks < 4; ++ks) {
            long am2 = *(const long*)&d1buf[(m2 * 16 + l16) * D_S + ks * 32 + koff];
            Cd2 = mfma_fp8(am2, bD2[ks], Cd2);
        }
        {
            const float db = d2_b[a * NH + dcol2 + l16];
            #pragma unroll
            for (int rg = 0; rg < 4; ++rg) {
                const int row = m2 * 16 + quad * 4 + rg;
                float v = Cd2[rg] + db;
                d2buf[row * D_S + dcol2 + l16] = f2e4m3(v > 0.f ? v : 0.f);
            }
        }
        __syncthreads();   // barrier 2 of 2

        // ============ heads + loss: waves 0-1; others run ahead ============
        if (tid < 128) {
            const int row = tid >> 2, o = tid & 3;
            float acc = (o < 2) ? m_b[a * 2 + o] : s_b[a * 2 + (o - 2)];
            const unsigned char* dp = &d2buf[row * D_S];
            const float* wp = &wls[o * NH];
            for (int k = 0; k < NH; k += 4) {
                acc += e4m32f(dp[k])     * wp[k]
                     + e4m32f(dp[k + 1]) * wp[k + 1]
                     + e4m32f(dp[k + 2]) * wp[k + 2]
                     + e4m32f(dp[k + 3]) * wp[k + 3];
            }
            const float v1 = __shfl_xor(acc, 1);
            const float v2 = __shfl_xor(acc, 2);
            const float v3 = __shfl_xor(acc, 3);
            if (o == 0) {
                const float* f0 = states + (((size_t)t * NA + a) * NB + (b0 + row)) * NY + 4 * a;
                const float* f1 = states + (((size_t)(t + 1) * NA + a) * NB + (b0 + row)) * NY + 4 * a;
                const float mm0 = acc, mm1 = v1;
                const float s0 = softp(v2), s1 = softp(v3);
                const float x0 = f1[2], x1 = f1[3];
                const float t0 = (x0 - mm0) / s0, t1 = (x1 - mm1) / s1;
                accL += 0.5f * (t0 * t0 + t1 * t1 + 2.f * (__logf(s0) + __logf(s1)) + 2.f * LOG2PI);
                const float e0 = f0[0] + f0[2] * FSC - f1[0];
                const float e1 = f0[1] + f0[3] * FSC - f1[1];
                accEp += sqrtf(e0 * e0 + e1 * e1);
                const float g0 = mm0 - x0, g1 = mm1 - x1;
                accEv += sqrtf(g0 * g0 + g1 * g1);
            }
        }
    }

    // ---- final reduction: accs live in waves 0-1 (lanes with o==0) ----
    if (tid < 128) {
        float L = accL, E = accEp, V = accEv;
        #pragma unroll
        for (int off = 32; off; off >>= 1) {
            L += __shfl_down(L, off);
            E += __shfl_down(E, off);
            V += __shfl_down(V, off);
        }
        if ((tid & 63) == 0) {
            const float inv = 1.f / (float)(NT * NA);
            atomicAdd(&out[0], L * inv);
            atomicAdd(&out[1], E * inv);
            atomicAdd(&out[2], V * inv);
        }
    }
}

extern "C" void kernel_launch(void* const* d_in, const int* in_sizes, int n_in,
                              void* d_out, int out_size, void* d_ws, size_t ws_size,
                              hipStream_t stream) {
    const float* states = (const float*)d_in[0];
    const float* w_ih   = (const float*)d_in[1];
    const float* w_hh   = (const float*)d_in[2];
    const float* b_ih   = (const float*)d_in[3];
    const float* b_hh   = (const float*)d_in[4];
    const float* d1_w   = (const float*)d_in[5];
    const float* d1_b   = (const float*)d_in[6];
    const float* d2_w   = (const float*)d_in[7];
    const float* d2_b   = (const float*)d_in[8];
    const float* m_w    = (const float*)d_in[9];
    const float* m_b    = (const float*)d_in[10];
    const float* s_w    = (const float*)d_in[11];
    const float* s_b    = (const float*)d_in[12];

    int* ctrl = (int*)d_ws;                       // [0..7] xcd counters, [16..335] claim flags
    unsigned char* Wrz = (unsigned char*)d_ws + 2048;
    unsigned char* Wni = Wrz + (size_t)NA * 512 * K1;
    unsigned char* Wnh = Wni + (size_t)NA * 256 * K1;
    unsigned char* D1  = Wnh + (size_t)NA * 256 * NR;
    unsigned char* D2  = D1  + (size_t)NA * NH * NR;

    hipMemsetAsync(d_out, 0, 3 * sizeof(float), stream);
    hipMemsetAsync(d_ws, 0, 2048, stream);

    const int nrz = NA * 512 * K1;
    k_prep_wrz<<<(nrz + 255) / 256, 256, 0, stream>>>(w_ih, w_hh, Wrz);
    const int nni = NA * 256 * K1;
    k_prep_wni<<<(nni + 255) / 256, 256, 0, stream>>>(w_ih, Wni);
    const int nnh = NA * 256 * NR;
    k_prep_wnh<<<(nnh + 255) / 256, 256, 0, stream>>>(w_hh, Wnh);
    const int nd1 = NA * NH * NR;
    k_convert<<<(nd1 + 255) / 256, 256, 0, stream>>>(d1_w, D1, nd1);
    const int nd2 = NA * NH * NH;
    k_convert<<<(nd2 + 255) / 256, 256, 0, stream>>>(d2_w, D2, nd2);

    k_main<<<dim3(NBLK), dim3(1024), 0, stream>>>(states, Wrz, Wni, Wnh, D1, D2,
                                                  b_ih, b_hh, d1_b, d2_b,
                                                  m_w, m_b, s_w, s_b, ctrl, (float*)d_out);
}

// Round 7
// 2456.149 us; speedup vs baseline: 1.7591x; 1.7591x over previous
//
#include <hip/hip_runtime.h>
#include <hip/hip_bf16.h>

// ---------------- problem constants ----------------
#define NA 10
#define NB 1024
#define NY 94
#define NR 256
#define NH 128
#define NT 50
#define FSC 0.1f
#define NIN 350
#define K1 384            // padded enc K: [h(256) | y(94) | pad(34)], multiple of 64
#define ENC_S 392         // enc LDS row stride (bytes): 8B-aligned, 98 dwords = 2 mod 32 banks
#define D1_S 136          // d1 LDS row stride (fp8 bytes)
#define D2_S 136          // d2 LDS row stride (bf16 shorts)
#define BT 64             // batch rows per block
#define NBLK 160
#define LOG2PI 1.8378770664093453f

typedef __attribute__((ext_vector_type(4))) float frag_f32;
typedef __attribute__((ext_vector_type(2))) long lv2;   // 16B = two fp8 k-fragments

__device__ __forceinline__ frag_f32 mfma_fp8(long a, long b, frag_f32 c) {
    return __builtin_amdgcn_mfma_f32_16x16x32_fp8_fp8(a, b, c, 0, 0, 0);
}

// dual-ks swizzle: within a 64-k block, bytes laid out quad-major so one 16B
// load at (k/64)*64 + quad*16 yields lane fragments for ks=2*(k/64) and ks+1.
__device__ __forceinline__ int swz(int k) {
    int ks = k >> 5, quad = (k >> 3) & 3, j = k & 7;
    return (ks >> 1) * 64 + quad * 16 + (ks & 1) * 8 + j;
}

// ---- OCP e4m3fn encode (RTNE, validated on HW in R6) ----
__device__ __forceinline__ unsigned char f2e4m3(float x) {
    unsigned int u = __float_as_uint(x);
    unsigned char s = (unsigned char)((u >> 24) & 0x80u);
    unsigned int a = u & 0x7FFFFFFFu;
    float af = __uint_as_float(a);
    if (af >= 448.f) return s | 0x7Eu;
    if (af < 0x1p-10f) return s;
    int e = (int)(a >> 23) - 127;
    if (e >= -6) {
        unsigned int r = a + 0x7FFFFu + ((a >> 20) & 1u);
        int e2 = (int)(r >> 23) - 127;
        unsigned int m = (r >> 20) & 7u;
        if (e2 > 8 || (e2 == 8 && m > 6)) return s | 0x7Eu;
        return s | (unsigned char)(((e2 + 7) << 3) | m);
    } else {
        int qi = (int)rintf(af * 512.f);
        return s | (unsigned char)qi;
    }
}
__device__ __forceinline__ unsigned short f2bf(float f) {
    unsigned int u = __float_as_uint(f);
    u = (u + 0x7fffu + ((u >> 16) & 1u)) >> 16;
    return (unsigned short)u;
}
__device__ __forceinline__ float bf2f(unsigned short h) {
    return __uint_as_float(((unsigned int)h) << 16);
}
__device__ __forceinline__ float sigm(float x) { return 1.f / (1.f + __expf(-x)); }
__device__ __forceinline__ float tanh_c(float x) {
    float xx = fminf(fmaxf(x, -15.f), 15.f);
    float e = __expf(2.f * xx);
    return (e - 1.f) / (e + 1.f);
}
__device__ __forceinline__ float softp(float x) {
    return fmaxf(x, 0.f) + log1pf(__expf(-fabsf(x)));
}

// ---------------- prep kernels: fp8 + swizzled dual-ks layout ----------------
// Wrz [A][512][K1]: rows 0..255 r, 256..511 z; k-space [h|y|pad]; h-part W_hh pre-added.
__global__ void k_prep_wrz(const float* __restrict__ w_ih, const float* __restrict__ w_hh,
                           unsigned char* __restrict__ dst) {
    int i = blockIdx.x * 256 + threadIdx.x;
    if (i >= NA * 512 * K1) return;
    int k = i % K1;
    int c = (i / K1) % 512;
    int a = i / (K1 * 512);
    float v = 0.f;
    if (k < 256)      v = w_ih[(size_t)(a * 768 + c) * NIN + NY + k] + w_hh[(size_t)(a * 768 + c) * NR + k];
    else if (k < 350) v = w_ih[(size_t)(a * 768 + c) * NIN + (k - 256)];
    dst[(size_t)(a * 512 + c) * K1 + swz(k)] = f2e4m3(v);
}
// Wni [A][256][K1]: i_n rows (768-space 512..767)
__global__ void k_prep_wni(const float* __restrict__ w_ih, unsigned char* __restrict__ dst) {
    int i = blockIdx.x * 256 + threadIdx.x;
    if (i >= NA * 256 * K1) return;
    int k = i % K1;
    int c = (i / K1) % 256;
    int a = i / (K1 * 256);
    float v = 0.f;
    if (k < 256)      v = w_ih[(size_t)(a * 768 + 512 + c) * NIN + NY + k];
    else if (k < 350) v = w_ih[(size_t)(a * 768 + 512 + c) * NIN + (k - 256)];
    dst[(size_t)(a * 256 + c) * K1 + swz(k)] = f2e4m3(v);
}
// Wnh [A][256][256]: h_n rows
__global__ void k_prep_wnh(const float* __restrict__ w_hh, unsigned char* __restrict__ dst) {
    int i = blockIdx.x * 256 + threadIdx.x;
    if (i >= NA * 256 * NR) return;
    int k = i % NR;
    int c = (i / NR) % 256;
    int a = i / (NR * 256);
    dst[(size_t)(a * 256 + c) * NR + swz(k)] = f2e4m3(w_hh[(size_t)(a * 768 + 512 + c) * NR + k]);
}
// D1 [A][128][256], D2 [A][128][128]
__global__ void k_prep_d1(const float* __restrict__ src, unsigned char* __restrict__ dst) {
    int i = blockIdx.x * 256 + threadIdx.x;
    if (i >= NA * NH * NR) return;
    int k = i % NR;
    int c = (i / NR) % NH;
    int a = i / (NR * NH);
    dst[(size_t)(a * NH + c) * NR + swz(k)] = f2e4m3(src[(size_t)(a * NH + c) * NR + k]);
}
__global__ void k_prep_d2(const float* __restrict__ src, unsigned char* __restrict__ dst) {
    int i = blockIdx.x * 256 + threadIdx.x;
    if (i >= NA * NH * NH) return;
    int k = i % NH;
    int c = (i / NH) % NH;
    int a = i / (NH * NH);
    dst[(size_t)(a * NH + c) * NH + swz(k)] = f2e4m3(src[(size_t)(a * NH + c) * NH + k]);
}

// ---------------- main persistent kernel ----------------
// 1024 threads = 16 waves, 1 block/CU (4 waves/SIMD, VGPR cap 128 -> no spill).
__launch_bounds__(1024, 4)
__global__ void k_main(const float* __restrict__ states,
                       const unsigned char* __restrict__ Wrz,
                       const unsigned char* __restrict__ Wni,
                       const unsigned char* __restrict__ Wnh,
                       const unsigned char* __restrict__ D1w,
                       const unsigned char* __restrict__ D2w,
                       const float* __restrict__ b_ih, const float* __restrict__ b_hh,
                       const float* __restrict__ d1_b, const float* __restrict__ d2_b,
                       const float* __restrict__ m_w,  const float* __restrict__ m_b,
                       const float* __restrict__ s_w,  const float* __restrict__ s_b,
                       int* __restrict__ ctrl,
                       float* __restrict__ out)
{
    __shared__ unsigned char  enc[2][BT * ENC_S];   // 2 x 25,088 B  [h(256)|y(94)|pad0(34)]
    __shared__ unsigned char  d1buf[BT * D1_S];     //  8,704 B (fp8, feeds pass C MFMA)
    __shared__ unsigned short d2buf[BT * D2_S];     // 17,408 B (bf16, feeds VALU heads)
    __shared__ float          wls[4 * NH];          //  2,048 B
    __shared__ int s_p;

    const int tid = threadIdx.x;

    // XCD-measured work claim (20 slots/XCD -> <=2 agents resident per L2)
    if (tid == 0) {
        unsigned int xcc = __builtin_amdgcn_s_getreg(63508) & 7u; // HW_REG_XCC_ID
        int slot = atomicAdd(&ctrl[xcc], 1);
        int p = -1;
        if (slot < 20) {
            int cand = (int)xcc * 20 + slot;
            if (atomicCAS(&ctrl[16 + cand], 0, 1) == 0) p = cand;
        }
        for (int i = 0; p < 0 && i < NBLK; ++i) {
            int cand = ((int)xcc * 20 + i) % NBLK;
            if (atomicCAS(&ctrl[16 + cand], 0, 1) == 0) p = cand;
        }
        s_p = p;
    }
    for (int i = tid; i < BT * ENC_S; i += 1024) { enc[0][i] = 0; enc[1][i] = 0; }
    __syncthreads();

    const int p  = s_p;
    const int a  = p >> 4;
    const int b0 = (p & 15) * BT;

    const int w    = tid >> 6;
    const int lane = tid & 63;
    const int quad = lane >> 4;
    const int l16  = lane & 15;
    const int c0   = w * 16;
    const int qo   = quad * 16;          // byte offset of this quad's 16B dual-unit
    const int ko8  = quad * 8;           // byte offset for single-ks LDS A-frags

    // per-wave swizzled weight row bases (+quad offset folded in)
    const unsigned char* rR  = Wrz + ((size_t)(a * 512 +       c0 + l16) * K1) + qo;
    const unsigned char* rZ  = Wrz + ((size_t)(a * 512 + 256 + c0 + l16) * K1) + qo;
    const unsigned char* rI  = Wni + ((size_t)(a * 256 + c0 + l16) * K1) + qo;
    const unsigned char* rH  = Wnh + ((size_t)(a * 256 + c0 + l16) * NR) + qo;
    const unsigned char* rD1 = D1w + ((size_t)(a * NH  + c0 + l16) * NR) + qo;
    const int dcol2 = (w >> 1) * 16;     // pass-C col tile
    const int m2    = (w & 1);           // pass-C row half (32 rows)
    const unsigned char* rD2 = D2w + ((size_t)(a * NH + dcol2 + l16) * NH) + qo;

    if (tid < 512) {
        int o = tid >> 7, k = tid & 127;
        wls[tid] = (o < 2) ? m_w[(size_t)(a * 2 + o) * NH + k]
                           : s_w[(size_t)(a * 2 + (o - 2)) * NH + k];
    }
    // stage y_0
    {
        const int row = tid >> 4, c6 = (tid & 15) * 6;
        const float* yp = states + (((size_t)0 * NA + a) * NB + (b0 + row)) * NY;
        #pragma unroll
        for (int j = 0; j < 6; ++j) {
            int c = c6 + j;
            if (c < NY) enc[0][row * ENC_S + 256 + c] = f2e4m3(yp[c]);
        }
    }
    float accL = 0.f, accEp = 0.f, accEv = 0.f;
    float hc[4][4];                      // fp32 h carry, this wave's (row,col) set
    #pragma unroll
    for (int mt = 0; mt < 4; ++mt)
        #pragma unroll
        for (int rg = 0; rg < 4; ++rg) hc[mt][rg] = 0.f;
    __syncthreads();

    const frag_f32 z4 = {0.f, 0.f, 0.f, 0.f};

    for (int t = 0; t < NT; ++t) {
        unsigned char* cur = enc[t & 1];
        unsigned char* nxt = enc[(t + 1) & 1];

        // ============ pass A: rz GEMM (12 ks) + d1 GEMM (8 ks, waves 0-7) ============
        frag_f32 Cr[4], Cz[4], Cd1[4];
        #pragma unroll
        for (int mt = 0; mt < 4; ++mt) { Cr[mt] = z4; Cz[mt] = z4; Cd1[mt] = z4; }
        lv2 Rb[2], Zb[2], Db[2];
        Rb[0] = *(const lv2*)(rR);
        Zb[0] = *(const lv2*)(rZ);
        if (w < 8) Db[0] = *(const lv2*)(rD1);
        #pragma unroll
        for (int du = 0; du < 6; ++du) {
            if (du + 1 < 6) {
                Rb[(du + 1) & 1] = *(const lv2*)(rR + (du + 1) * 64);
                Zb[(du + 1) & 1] = *(const lv2*)(rZ + (du + 1) * 64);
            }
            if (w < 8 && du + 1 < 4) Db[(du + 1) & 1] = *(const lv2*)(rD1 + (du + 1) * 64);
            #pragma unroll
            for (int kp = 0; kp < 2; ++kp) {
                const int ks = du * 2 + kp;
                long am[4];
                #pragma unroll
                for (int mt = 0; mt < 4; ++mt)
                    am[mt] = *(const long*)&cur[(mt * 16 + l16) * ENC_S + ks * 32 + ko8];
                #pragma unroll
                for (int mt = 0; mt < 4; ++mt) {
                    Cr[mt] = mfma_fp8(am[mt], Rb[du & 1][kp], Cr[mt]);
                    Cz[mt] = mfma_fp8(am[mt], Zb[du & 1][kp], Cz[mt]);
                }
                if (w < 8 && du < 4) {
                    #pragma unroll
                    for (int mt = 0; mt < 4; ++mt)
                        Cd1[mt] = mfma_fp8(am[mt], Db[du & 1][kp], Cd1[mt]);
                }
            }
        }
        // ---- epilogue A: d1 relu -> fp8 LDS; r,z -> sigmoid in regs ----
        if (w < 8) {
            const float db = d1_b[a * NH + c0 + l16];
            #pragma unroll
            for (int mt = 0; mt < 4; ++mt)
                #pragma unroll
                for (int rg = 0; rg < 4; ++rg) {
                    const int row = mt * 16 + quad * 4 + rg;
                    float v = Cd1[mt][rg] + db;
                    d1buf[row * D1_S + c0 + l16] = f2e4m3(v > 0.f ? v : 0.f);
                }
        }
        {
            const int col = c0 + l16;
            const float brz = b_ih[a * 768 + col]       + b_hh[a * 768 + col];
            const float bzz = b_ih[a * 768 + 256 + col] + b_hh[a * 768 + 256 + col];
            #pragma unroll
            for (int mt = 0; mt < 4; ++mt)
                #pragma unroll
                for (int rg = 0; rg < 4; ++rg) {
                    Cr[mt][rg] = sigm(Cr[mt][rg] + brz);
                    Cz[mt][rg] = sigm(Cz[mt][rg] + bzz);
                }
        }

        // ============ pass B: i_n (12 ks) + h_n (8 ks) ============
        frag_f32 Ci[4], Ch[4];
        #pragma unroll
        for (int mt = 0; mt < 4; ++mt) { Ci[mt] = z4; Ch[mt] = z4; }
        lv2 Ib[2], Hb[2];
        Ib[0] = *(const lv2*)(rI);
        Hb[0] = *(const lv2*)(rH);
        #pragma unroll
        for (int du = 0; du < 6; ++du) {
            if (du + 1 < 6) Ib[(du + 1) & 1] = *(const lv2*)(rI + (du + 1) * 64);
            if (du + 1 < 4) Hb[(du + 1) & 1] = *(const lv2*)(rH + (du + 1) * 64);
            #pragma unroll
            for (int kp = 0; kp < 2; ++kp) {
                const int ks = du * 2 + kp;
                long am[4];
                #pragma unroll
                for (int mt = 0; mt < 4; ++mt)
                    am[mt] = *(const long*)&cur[(mt * 16 + l16) * ENC_S + ks * 32 + ko8];
                #pragma unroll
                for (int mt = 0; mt < 4; ++mt) {
                    Ci[mt] = mfma_fp8(am[mt], Ib[du & 1][kp], Ci[mt]);
                    if (du < 4) Ch[mt] = mfma_fp8(am[mt], Hb[du & 1][kp], Ch[mt]);
                }
            }
        }
        // ---- epilogue B: gates, fp32 reg carry, fp8 h to nxt ----
        {
            const int col = c0 + l16;
            const float bin = b_ih[a * 768 + 512 + col];
            const float bhn = b_hh[a * 768 + 512 + col];
            #pragma unroll
            for (int mt = 0; mt < 4; ++mt)
                #pragma unroll
                for (int rg = 0; rg < 4; ++rg) {
                    const int row = mt * 16 + quad * 4 + rg;
                    const float r = Cr[mt][rg];
                    const float z = Cz[mt][rg];
                    const float n = tanh_c(Ci[mt][rg] + bin + r * (Ch[mt][rg] + bhn));
                    const float hnew = (1.f - z) * n + z * hc[mt][rg];
                    hc[mt][rg] = hnew;
                    nxt[row * ENC_S + col] = f2e4m3(hnew);
                }
        }
        // ---- stage y_{t+1} ----
        {
            const int row = tid >> 4, c6 = (tid & 15) * 6;
            const float* yp = states + (((size_t)(t + 1) * NA + a) * NB + (b0 + row)) * NY;
            #pragma unroll
            for (int j = 0; j < 6; ++j) {
                int c = c6 + j;
                if (c < NY) nxt[row * ENC_S + 256 + c] = f2e4m3(yp[c]);
            }
        }
        // ---- prefetch d2 weights (2 duals) ----
        lv2 W2[2];
        W2[0] = *(const lv2*)(rD2);
        W2[1] = *(const lv2*)(rD2 + 64);
        __syncthreads();   // barrier 1 of 2

        // ============ pass C: d2 GEMM (4 ks), 16 waves: 8 col-tiles x 2 row-halves ============
        frag_f32 Cd2[2] = {z4, z4};
        #pragma unroll
        for (int du = 0; du < 2; ++du)
            #pragma unroll
            for (int kp = 0; kp < 2; ++kp) {
                const int ks = du * 2 + kp;
                #pragma unroll
                for (int mi = 0; mi < 2; ++mi) {
                    long am2 = *(const long*)&d1buf[(m2 * 32 + mi * 16 + l16) * D1_S + ks * 32 + ko8];
                    Cd2[mi] = mfma_fp8(am2, W2[du][kp], Cd2[mi]);
                }
            }
        {
            const float db = d2_b[a * NH + dcol2 + l16];
            #pragma unroll
            for (int mi = 0; mi < 2; ++mi)
                #pragma unroll
                for (int rg = 0; rg < 4; ++rg) {
                    const int row = m2 * 32 + mi * 16 + quad * 4 + rg;
                    float v = Cd2[mi][rg] + db;
                    d2buf[row * D2_S + dcol2 + l16] = f2bf(v > 0.f ? v : 0.f);
                }
        }
        __syncthreads();   // barrier 2 of 2

        // ============ heads + loss: waves 0-3; waves 4-15 run ahead ============
        if (tid < 256) {
            const int row = tid >> 2, o = tid & 3;
            float acc = (o < 2) ? m_b[a * 2 + o] : s_b[a * 2 + (o - 2)];
            const unsigned short* dp = &d2buf[row * D2_S];
            const float* wp = &wls[o * NH];
            #pragma unroll
            for (int kb = 0; kb < 16; ++kb) {
                #pragma unroll
                for (int j = 0; j < 8; ++j)
                    acc += bf2f(dp[kb * 8 + j]) * wp[kb * 8 + j];
            }
            const float v1 = __shfl_xor(acc, 1);
            const float v2 = __shfl_xor(acc, 2);
            const float v3 = __shfl_xor(acc, 3);
            if (o == 0) {
                const float* f0 = states + (((size_t)t * NA + a) * NB + (b0 + row)) * NY + 4 * a;
                const float* f1 = states + (((size_t)(t + 1) * NA + a) * NB + (b0 + row)) * NY + 4 * a;
                const float mm0 = acc, mm1 = v1;
                const float s0 = softp(v2), s1 = softp(v3);
                const float x0 = f1[2], x1 = f1[3];
                const float t0 = (x0 - mm0) / s0, t1 = (x1 - mm1) / s1;
                accL += 0.5f * (t0 * t0 + t1 * t1 + 2.f * (__logf(s0) + __logf(s1)) + 2.f * LOG2PI);
                const float e0 = f0[0] + f0[2] * FSC - f1[0];
                const float e1 = f0[1] + f0[3] * FSC - f1[1];
                accEp += sqrtf(e0 * e0 + e1 * e1);
                const float g0 = mm0 - x0, g1 = mm1 - x1;
                accEv += sqrtf(g0 * g0 + g1 * g1);
            }
        }
    }

    // ---- final reduction ----
    if (tid < 256) {
        float L = accL, E = accEp, V = accEv;
        #pragma unroll
        for (int off = 32; off; off >>= 1) {
            L += __shfl_down(L, off);
            E += __shfl_down(E, off);
            V += __shfl_down(V, off);
        }
        if ((tid & 63) == 0) {
            const float inv = 1.f / (float)(NT * NA);
            atomicAdd(&out[0], L * inv);
            atomicAdd(&out[1], E * inv);
            atomicAdd(&out[2], V * inv);
        }
    }
}

extern "C" void kernel_launch(void* const* d_in, const int* in_sizes, int n_in,
                              void* d_out, int out_size, void* d_ws, size_t ws_size,
                              hipStream_t stream) {
    const float* states = (const float*)d_in[0];
    const float* w_ih   = (const float*)d_in[1];
    const float* w_hh   = (const float*)d_in[2];
    const float* b_ih   = (const float*)d_in[3];
    const float* b_hh   = (const float*)d_in[4];
    const float* d1_w   = (const float*)d_in[5];
    const float* d1_b   = (const float*)d_in[6];
    const float* d2_w   = (const float*)d_in[7];
    const float* d2_b   = (const float*)d_in[8];
    const float* m_w    = (const float*)d_in[9];
    const float* m_b    = (const float*)d_in[10];
    const float* s_w    = (const float*)d_in[11];
    const float* s_b    = (const float*)d_in[12];

    int* ctrl = (int*)d_ws;                       // [0..7] xcd counters, [16..175] claim flags
    unsigned char* Wrz = (unsigned char*)d_ws + 2048;
    unsigned char* Wni = Wrz + (size_t)NA * 512 * K1;
    unsigned char* Wnh = Wni + (size_t)NA * 256 * K1;
    unsigned char* D1  = Wnh + (size_t)NA * 256 * NR;
    unsigned char* D2  = D1  + (size_t)NA * NH * NR;

    hipMemsetAsync(d_out, 0, 3 * sizeof(float), stream);
    hipMemsetAsync(d_ws, 0, 2048, stream);

    const int nrz = NA * 512 * K1;
    k_prep_wrz<<<(nrz + 255) / 256, 256, 0, stream>>>(w_ih, w_hh, Wrz);
    const int nni = NA * 256 * K1;
    k_prep_wni<<<(nni + 255) / 256, 256, 0, stream>>>(w_ih, Wni);
    const int nnh = NA * 256 * NR;
    k_prep_wnh<<<(nnh + 255) / 256, 256, 0, stream>>>(w_hh, Wnh);
    const int nd1 = NA * NH * NR;
    k_prep_d1<<<(nd1 + 255) / 256, 256, 0, stream>>>(d1_w, D1);
    const int nd2 = NA * NH * NH;
    k_prep_d2<<<(nd2 + 255) / 256, 256, 0, stream>>>(d2_w, D2);

    k_main<<<dim3(NBLK), dim3(1024), 0, stream>>>(states, Wrz, Wni, Wnh, D1, D2,
                                                  b_ih, b_hh, d1_b, d2_b,
                                                  m_w, m_b, s_w, s_b, ctrl, (float*)d_out);
}

// Round 8
// 1625.536 us; speedup vs baseline: 2.6580x; 1.5110x over previous
//
#include <hip/hip_runtime.h>
#include <hip/hip_bf16.h>

// ---------------- problem constants ----------------
#define NA 10
#define NB 1024
#define NY 94
#define NR 256
#define NH 128
#define NT 50
#define FSC 0.1f
#define NIN 350
#define K1 384            // padded enc K: [h(256) | y(94) | pad(34)], multiple of 64
#define ENC_S 392         // enc LDS row stride (fp8 bytes), 8B-aligned
#define H2_S 264          // bf16 h-carry row stride (shorts) -> 528 B
#define D1_S 136          // d1 LDS row stride (fp8 bytes)
#define D2_S 136          // d2 LDS row stride (bf16 shorts)
#define BT 64             // batch rows per block
#define NBLK 160
#define LOG2PI 1.8378770664093453f

typedef __attribute__((ext_vector_type(4))) float frag_f32;
typedef __attribute__((ext_vector_type(2))) long lv2;   // 16B = two fp8 k-fragments

__device__ __forceinline__ frag_f32 mfma_fp8(long a, long b, frag_f32 c) {
    return __builtin_amdgcn_mfma_f32_16x16x32_fp8_fp8(a, b, c, 0, 0, 0);
}

// dual-ks swizzle: one 16B load per quad yields fragments for ks and ks+1
__device__ __forceinline__ int swz(int k) {
    int ks = k >> 5, quad = (k >> 3) & 3, j = k & 7;
    return (ks >> 1) * 64 + quad * 16 + (ks & 1) * 8 + j;
}

// ---- OCP e4m3fn encode (RTNE, HW-validated R6/R7) ----
__device__ __forceinline__ unsigned char f2e4m3(float x) {
    unsigned int u = __float_as_uint(x);
    unsigned char s = (unsigned char)((u >> 24) & 0x80u);
    unsigned int a = u & 0x7FFFFFFFu;
    float af = __uint_as_float(a);
    if (af >= 448.f) return s | 0x7Eu;
    if (af < 0x1p-10f) return s;
    int e = (int)(a >> 23) - 127;
    if (e >= -6) {
        unsigned int r = a + 0x7FFFFu + ((a >> 20) & 1u);
        int e2 = (int)(r >> 23) - 127;
        unsigned int m = (r >> 20) & 7u;
        if (e2 > 8 || (e2 == 8 && m > 6)) return s | 0x7Eu;
        return s | (unsigned char)(((e2 + 7) << 3) | m);
    } else {
        int qi = (int)rintf(af * 512.f);
        return s | (unsigned char)qi;
    }
}
__device__ __forceinline__ unsigned short f2bf(float f) {
    unsigned int u = __float_as_uint(f);
    u = (u + 0x7fffu + ((u >> 16) & 1u)) >> 16;
    return (unsigned short)u;
}
__device__ __forceinline__ float bf2f(unsigned short h) {
    return __uint_as_float(((unsigned int)h) << 16);
}
__device__ __forceinline__ float sigm(float x) { return 1.f / (1.f + __expf(-x)); }
__device__ __forceinline__ float tanh_c(float x) {
    float xx = fminf(fmaxf(x, -15.f), 15.f);
    float e = __expf(2.f * xx);
    return (e - 1.f) / (e + 1.f);
}
__device__ __forceinline__ float softp(float x) {
    return fmaxf(x, 0.f) + log1pf(__expf(-fabsf(x)));
}

// ---------------- prep kernels: fp8 + swizzled dual-ks layout ----------------
__global__ void k_prep_wrz(const float* __restrict__ w_ih, const float* __restrict__ w_hh,
                           unsigned char* __restrict__ dst) {
    int i = blockIdx.x * 256 + threadIdx.x;
    if (i >= NA * 512 * K1) return;
    int k = i % K1;
    int c = (i / K1) % 512;
    int a = i / (K1 * 512);
    float v = 0.f;
    if (k < 256)      v = w_ih[(size_t)(a * 768 + c) * NIN + NY + k] + w_hh[(size_t)(a * 768 + c) * NR + k];
    else if (k < 350) v = w_ih[(size_t)(a * 768 + c) * NIN + (k - 256)];
    dst[(size_t)(a * 512 + c) * K1 + swz(k)] = f2e4m3(v);
}
__global__ void k_prep_wni(const float* __restrict__ w_ih, unsigned char* __restrict__ dst) {
    int i = blockIdx.x * 256 + threadIdx.x;
    if (i >= NA * 256 * K1) return;
    int k = i % K1;
    int c = (i / K1) % 256;
    int a = i / (K1 * 256);
    float v = 0.f;
    if (k < 256)      v = w_ih[(size_t)(a * 768 + 512 + c) * NIN + NY + k];
    else if (k < 350) v = w_ih[(size_t)(a * 768 + 512 + c) * NIN + (k - 256)];
    dst[(size_t)(a * 256 + c) * K1 + swz(k)] = f2e4m3(v);
}
__global__ void k_prep_wnh(const float* __restrict__ w_hh, unsigned char* __restrict__ dst) {
    int i = blockIdx.x * 256 + threadIdx.x;
    if (i >= NA * 256 * NR) return;
    int k = i % NR;
    int c = (i / NR) % 256;
    int a = i / (NR * 256);
    dst[(size_t)(a * 256 + c) * NR + swz(k)] = f2e4m3(w_hh[(size_t)(a * 768 + 512 + c) * NR + k]);
}
__global__ void k_prep_d1(const float* __restrict__ src, unsigned char* __restrict__ dst) {
    int i = blockIdx.x * 256 + threadIdx.x;
    if (i >= NA * NH * NR) return;
    int k = i % NR;
    int c = (i / NR) % NH;
    int a = i / (NR * NH);
    dst[(size_t)(a * NH + c) * NR + swz(k)] = f2e4m3(src[(size_t)(a * NH + c) * NR + k]);
}
__global__ void k_prep_d2(const float* __restrict__ src, unsigned char* __restrict__ dst) {
    int i = blockIdx.x * 256 + threadIdx.x;
    if (i >= NA * NH * NH) return;
    int k = i % NH;
    int c = (i / NH) % NH;
    int a = i / (NH * NH);
    dst[(size_t)(a * NH + c) * NH + swz(k)] = f2e4m3(src[(size_t)(a * NH + c) * NH + k]);
}

// ---------------- main persistent kernel ----------------
// 1024 threads = 16 waves. 1024-thr block => 4 waves/SIMD => 128 regs/lane total
// (64 arch + 64 acc). Arch live-set kept ~50 (R3-proven); accumulators in acc half.
__launch_bounds__(1024, 4)
__global__ void k_main(const float* __restrict__ states,
                       const unsigned char* __restrict__ Wrz,
                       const unsigned char* __restrict__ Wni,
                       const unsigned char* __restrict__ Wnh,
                       const unsigned char* __restrict__ D1w,
                       const unsigned char* __restrict__ D2w,
                       const float* __restrict__ b_ih, const float* __restrict__ b_hh,
                       const float* __restrict__ d1_b, const float* __restrict__ d2_b,
                       const float* __restrict__ m_w,  const float* __restrict__ m_b,
                       const float* __restrict__ s_w,  const float* __restrict__ s_b,
                       int* __restrict__ ctrl,
                       float* __restrict__ out)
{
    __shared__ unsigned char  enc[2][BT * ENC_S];   // 50,176 B  fp8 [h|y|pad0]
    __shared__ unsigned short hbf[BT * H2_S];       // 33,792 B  bf16 h carry
    __shared__ unsigned char  d1buf[BT * D1_S];     //  8,704 B  fp8
    __shared__ unsigned short d2buf[BT * D2_S];     // 17,408 B  bf16
    __shared__ float          wls[4 * NH];          //  2,048 B  head weights
    __shared__ float          bls[1408];            //  5,632 B  biases: brz|bzz|bin|bhn|d1b|d2b
    __shared__ int s_p;

    const int tid = threadIdx.x;

    // XCD-measured work claim (<=2 agents per XCD L2)
    if (tid == 0) {
        unsigned int xcc = __builtin_amdgcn_s_getreg(63508) & 7u; // HW_REG_XCC_ID
        int slot = atomicAdd(&ctrl[xcc], 1);
        int p = -1;
        if (slot < 20) {
            int cand = (int)xcc * 20 + slot;
            if (atomicCAS(&ctrl[16 + cand], 0, 1) == 0) p = cand;
        }
        for (int i = 0; p < 0 && i < NBLK; ++i) {
            int cand = ((int)xcc * 20 + i) % NBLK;
            if (atomicCAS(&ctrl[16 + cand], 0, 1) == 0) p = cand;
        }
        s_p = p;
    }
    for (int i = tid; i < BT * ENC_S; i += 1024) { enc[0][i] = 0; enc[1][i] = 0; }
    for (int i = tid; i < BT * H2_S;  i += 1024) hbf[i] = 0;
    __syncthreads();

    const int p  = s_p;
    const int a  = p >> 4;
    const int b0 = (p & 15) * BT;

    const int w    = tid >> 6;
    const int lane = tid & 63;
    const int quad = lane >> 4;
    const int l16  = lane & 15;
    const int c0   = w * 16;
    const int qo   = quad * 16;          // byte offset of this quad's 16B dual-unit
    const int ko8  = quad * 8;           // byte offset for single-ks LDS A-frags

    const unsigned char* rR  = Wrz + ((size_t)(a * 512 +       c0 + l16) * K1) + qo;
    const unsigned char* rZ  = Wrz + ((size_t)(a * 512 + 256 + c0 + l16) * K1) + qo;
    const unsigned char* rI  = Wni + ((size_t)(a * 256 + c0 + l16) * K1) + qo;
    const unsigned char* rH  = Wnh + ((size_t)(a * 256 + c0 + l16) * NR) + qo;
    const unsigned char* rD1 = D1w + ((size_t)(a * NH  + c0 + l16) * NR) + qo;
    const int dcol2 = (w >> 1) * 16;
    const int m2    = (w & 1);
    const unsigned char* rD2 = D2w + ((size_t)(a * NH + dcol2 + l16) * NH) + qo;

    // stage head weights + biases once
    if (tid < 512) {
        int o = tid >> 7, k = tid & 127;
        wls[tid] = (o < 2) ? m_w[(size_t)(a * 2 + o) * NH + k]
                           : s_w[(size_t)(a * 2 + (o - 2)) * NH + k];
    }
    if (tid < 256) {
        bls[tid]       = b_ih[a * 768 + tid]       + b_hh[a * 768 + tid];
        bls[256 + tid] = b_ih[a * 768 + 256 + tid] + b_hh[a * 768 + 256 + tid];
        bls[512 + tid] = b_ih[a * 768 + 512 + tid];
        bls[768 + tid] = b_hh[a * 768 + 512 + tid];
        if (tid < 128) {
            bls[1024 + tid] = d1_b[a * NH + tid];
            bls[1152 + tid] = d2_b[a * NH + tid];
        }
    }
    // stage y_0
    {
        const int row = tid >> 4, c6 = (tid & 15) * 6;
        const float* yp = states + (((size_t)0 * NA + a) * NB + (b0 + row)) * NY;
        #pragma unroll
        for (int j = 0; j < 6; ++j) {
            int c = c6 + j;
            if (c < NY) enc[0][row * ENC_S + 256 + c] = f2e4m3(yp[c]);
        }
    }
    float accL = 0.f, accEp = 0.f, accEv = 0.f;
    __syncthreads();

    const frag_f32 z4 = {0.f, 0.f, 0.f, 0.f};

    for (int t = 0; t < NT; ++t) {
        unsigned char* cur = enc[t & 1];
        unsigned char* nxt = enc[(t + 1) & 1];

        // ============ pass A: rz GEMM (12 ks) + d1 GEMM (8 ks, waves 0-7) ============
        frag_f32 Cr[4], Cz[4], Cd1[4];
        #pragma unroll
        for (int mt = 0; mt < 4; ++mt) { Cr[mt] = z4; Cz[mt] = z4; Cd1[mt] = z4; }
        lv2 Rb[2], Zb[2], Db[2];
        Rb[0] = *(const lv2*)(rR);
        Zb[0] = *(const lv2*)(rZ);
        if (w < 8) Db[0] = *(const lv2*)(rD1);
        #pragma unroll
        for (int du = 0; du < 6; ++du) {
            if (du + 1 < 6) {
                Rb[(du + 1) & 1] = *(const lv2*)(rR + (du + 1) * 64);
                Zb[(du + 1) & 1] = *(const lv2*)(rZ + (du + 1) * 64);
            }
            if (w < 8 && du + 1 < 4) Db[(du + 1) & 1] = *(const lv2*)(rD1 + (du + 1) * 64);
            #pragma unroll
            for (int kp = 0; kp < 2; ++kp) {
                const int ks = du * 2 + kp;
                long am[4];
                #pragma unroll
                for (int mt = 0; mt < 4; ++mt)
                    am[mt] = *(const long*)&cur[(mt * 16 + l16) * ENC_S + ks * 32 + ko8];
                #pragma unroll
                for (int mt = 0; mt < 4; ++mt) {
                    Cr[mt] = mfma_fp8(am[mt], Rb[du & 1][kp], Cr[mt]);
                    Cz[mt] = mfma_fp8(am[mt], Zb[du & 1][kp], Cz[mt]);
                }
                if (w < 8 && du < 4) {
                    #pragma unroll
                    for (int mt = 0; mt < 4; ++mt)
                        Cd1[mt] = mfma_fp8(am[mt], Db[du & 1][kp], Cd1[mt]);
                }
            }
        }
        // ---- epilogue A: d1 relu -> fp8 LDS; r,z -> sigmoid in regs ----
        if (w < 8) {
            const float db = bls[1024 + c0 + l16];
            #pragma unroll
            for (int mt = 0; mt < 4; ++mt)
                #pragma unroll
                for (int rg = 0; rg < 4; ++rg) {
                    const int row = mt * 16 + quad * 4 + rg;
                    float v = Cd1[mt][rg] + db;
                    d1buf[row * D1_S + c0 + l16] = f2e4m3(v > 0.f ? v : 0.f);
                }
        }
        {
            const int col = c0 + l16;
            const float brz = bls[col];
            const float bzz = bls[256 + col];
            #pragma unroll
            for (int mt = 0; mt < 4; ++mt)
                #pragma unroll
                for (int rg = 0; rg < 4; ++rg) {
                    Cr[mt][rg] = sigm(Cr[mt][rg] + brz);
                    Cz[mt][rg] = sigm(Cz[mt][rg] + bzz);
                }
        }

        // ============ pass B: i_n (12 ks) + h_n (8 ks) ============
        frag_f32 Ci[4], Ch[4];
        #pragma unroll
        for (int mt = 0; mt < 4; ++mt) { Ci[mt] = z4; Ch[mt] = z4; }
        lv2 Ib[2], Hb[2];
        Ib[0] = *(const lv2*)(rI);
        Hb[0] = *(const lv2*)(rH);
        #pragma unroll
        for (int du = 0; du < 6; ++du) {
            if (du + 1 < 6) Ib[(du + 1) & 1] = *(const lv2*)(rI + (du + 1) * 64);
            if (du + 1 < 4) Hb[(du + 1) & 1] = *(const lv2*)(rH + (du + 1) * 64);
            #pragma unroll
            for (int kp = 0; kp < 2; ++kp) {
                const int ks = du * 2 + kp;
                long am[4];
                #pragma unroll
                for (int mt = 0; mt < 4; ++mt)
                    am[mt] = *(const long*)&cur[(mt * 16 + l16) * ENC_S + ks * 32 + ko8];
                #pragma unroll
                for (int mt = 0; mt < 4; ++mt) {
                    Ci[mt] = mfma_fp8(am[mt], Ib[du & 1][kp], Ci[mt]);
                    if (du < 4) Ch[mt] = mfma_fp8(am[mt], Hb[du & 1][kp], Ch[mt]);
                }
            }
        }
        // ---- epilogue B: gates, bf16 h carry in LDS, fp8 h to nxt ----
        {
            const int col = c0 + l16;
            const float bin = bls[512 + col];
            const float bhn = bls[768 + col];
            #pragma unroll
            for (int mt = 0; mt < 4; ++mt)
                #pragma unroll
                for (int rg = 0; rg < 4; ++rg) {
                    const int row = mt * 16 + quad * 4 + rg;
                    const float r = Cr[mt][rg];
                    const float z = Cz[mt][rg];
                    const float n = tanh_c(Ci[mt][rg] + bin + r * (Ch[mt][rg] + bhn));
                    const float hold = bf2f(hbf[row * H2_S + col]);
                    const float hnew = (1.f - z) * n + z * hold;
                    hbf[row * H2_S + col] = f2bf(hnew);
                    nxt[row * ENC_S + col] = f2e4m3(hnew);
                }
        }
        // ---- stage y_{t+1} ----
        {
            const int row = tid >> 4, c6 = (tid & 15) * 6;
            const float* yp = states + (((size_t)(t + 1) * NA + a) * NB + (b0 + row)) * NY;
            #pragma unroll
            for (int j = 0; j < 6; ++j) {
                int c = c6 + j;
                if (c < NY) nxt[row * ENC_S + 256 + c] = f2e4m3(yp[c]);
            }
        }
        // ---- prefetch d2 weights (2 x 16B, L2-hit) ----
        lv2 W2[2];
        W2[0] = *(const lv2*)(rD2);
        W2[1] = *(const lv2*)(rD2 + 64);
        __syncthreads();   // barrier 1 of 2

        // ============ pass C: d2 GEMM (4 ks), 16 waves: 8 col-tiles x 2 row-halves ============
        frag_f32 Cd2[2] = {z4, z4};
        #pragma unroll
        for (int du = 0; du < 2; ++du)
            #pragma unroll
            for (int kp = 0; kp < 2; ++kp) {
                const int ks = du * 2 + kp;
                #pragma unroll
                for (int mi = 0; mi < 2; ++mi) {
                    long am2 = *(const long*)&d1buf[(m2 * 32 + mi * 16 + l16) * D1_S + ks * 32 + ko8];
                    Cd2[mi] = mfma_fp8(am2, W2[du][kp], Cd2[mi]);
                }
            }
        {
            const float db = bls[1152 + dcol2 + l16];
            #pragma unroll
            for (int mi = 0; mi < 2; ++mi)
                #pragma unroll
                for (int rg = 0; rg < 4; ++rg) {
                    const int row = m2 * 32 + mi * 16 + quad * 4 + rg;
                    float v = Cd2[mi][rg] + db;
                    d2buf[row * D2_S + dcol2 + l16] = f2bf(v > 0.f ? v : 0.f);
                }
        }
        __syncthreads();   // barrier 2 of 2

        // ============ heads + loss: waves 0-3; waves 4-15 run ahead ============
        if (tid < 256) {
            const int row = tid >> 2, o = tid & 3;
            float acc = (o < 2) ? m_b[a * 2 + o] : s_b[a * 2 + (o - 2)];
            const unsigned short* dp = &d2buf[row * D2_S];
            const float* wp = &wls[o * NH];
            #pragma unroll
            for (int kb = 0; kb < 16; ++kb) {
                #pragma unroll
                for (int j = 0; j < 8; ++j)
                    acc += bf2f(dp[kb * 8 + j]) * wp[kb * 8 + j];
            }
            const float v1 = __shfl_xor(acc, 1);
            const float v2 = __shfl_xor(acc, 2);
            const float v3 = __shfl_xor(acc, 3);
            if (o == 0) {
                const float* f0 = states + (((size_t)t * NA + a) * NB + (b0 + row)) * NY + 4 * a;
                const float* f1 = states + (((size_t)(t + 1) * NA + a) * NB + (b0 + row)) * NY + 4 * a;
                const float mm0 = acc, mm1 = v1;
                const float s0 = softp(v2), s1 = softp(v3);
                const float x0 = f1[2], x1 = f1[3];
                const float t0 = (x0 - mm0) / s0, t1 = (x1 - mm1) / s1;
                accL += 0.5f * (t0 * t0 + t1 * t1 + 2.f * (__logf(s0) + __logf(s1)) + 2.f * LOG2PI);
                const float e0 = f0[0] + f0[2] * FSC - f1[0];
                const float e1 = f0[1] + f0[3] * FSC - f1[1];
                accEp += sqrtf(e0 * e0 + e1 * e1);
                const float g0 = mm0 - x0, g1 = mm1 - x1;
                accEv += sqrtf(g0 * g0 + g1 * g1);
            }
        }
    }

    // ---- final reduction ----
    if (tid < 256) {
        float L = accL, E = accEp, V = accEv;
        #pragma unroll
        for (int off = 32; off; off >>= 1) {
            L += __shfl_down(L, off);
            E += __shfl_down(E, off);
            V += __shfl_down(V, off);
        }
        if ((tid & 63) == 0) {
            const float inv = 1.f / (float)(NT * NA);
            atomicAdd(&out[0], L * inv);
            atomicAdd(&out[1], E * inv);
            atomicAdd(&out[2], V * inv);
        }
    }
}

extern "C" void kernel_launch(void* const* d_in, const int* in_sizes, int n_in,
                              void* d_out, int out_size, void* d_ws, size_t ws_size,
                              hipStream_t stream) {
    const float* states = (const float*)d_in[0];
    const float* w_ih   = (const float*)d_in[1];
    const float* w_hh   = (const float*)d_in[2];
    const float* b_ih   = (const float*)d_in[3];
    const float* b_hh   = (const float*)d_in[4];
    const float* d1_w   = (const float*)d_in[5];
    const float* d1_b   = (const float*)d_in[6];
    const float* d2_w   = (const float*)d_in[7];
    const float* d2_b   = (const float*)d_in[8];
    const float* m_w    = (const float*)d_in[9];
    const float* m_b    = (const float*)d_in[10];
    const float* s_w    = (const float*)d_in[11];
    const float* s_b    = (const float*)d_in[12];

    int* ctrl = (int*)d_ws;
    unsigned char* Wrz = (unsigned char*)d_ws + 2048;
    unsigned char* Wni = Wrz + (size_t)NA * 512 * K1;
    unsigned char* Wnh = Wni + (size_t)NA * 256 * K1;
    unsigned char* D1  = Wnh + (size_t)NA * 256 * NR;
    unsigned char* D2  = D1  + (size_t)NA * NH * NR;

    hipMemsetAsync(d_out, 0, 3 * sizeof(float), stream);
    hipMemsetAsync(d_ws, 0, 2048, stream);

    const int nrz = NA * 512 * K1;
    k_prep_wrz<<<(nrz + 255) / 256, 256, 0, stream>>>(w_ih, w_hh, Wrz);
    const int nni = NA * 256 * K1;
    k_prep_wni<<<(nni + 255) / 256, 256, 0, stream>>>(w_ih, Wni);
    const int nnh = NA * 256 * NR;
    k_prep_wnh<<<(nnh + 255) / 256, 256, 0, stream>>>(w_hh, Wnh);
    const int nd1 = NA * NH * NR;
    k_prep_d1<<<(nd1 + 255) / 256, 256, 0, stream>>>(d1_w, D1);
    const int nd2 = NA * NH * NH;
    k_prep_d2<<<(nd2 + 255) / 256, 256, 0, stream>>>(d2_w, D2);

    k_main<<<dim3(NBLK), dim3(1024), 0, stream>>>(states, Wrz, Wni, Wnh, D1, D2,
                                                  b_ih, b_hh, d1_b, d2_b,
                                                  m_w, m_b, s_w, s_b, ctrl, (float*)d_out);
}